// Round 1
// baseline (1814.188 us; speedup 1.0000x reference)
//
#include <hip/hip_runtime.h>

#define NNODES 100000
#define NEDGES 1600000
#define HDIM 64

// ---------------- degree ----------------
__global__ void deg_init(float* deg, int n) {
    int i = blockIdx.x * blockDim.x + threadIdx.x;
    if (i < n) deg[i] = 1.0f;  // self-loop
}

__global__ void deg_count(const int* __restrict__ dst, float* deg, int ne) {
    int i = blockIdx.x * blockDim.x + threadIdx.x;
    if (i < ne) atomicAdd(&deg[dst[i]], 1.0f);
}

__global__ void make_dinv(float* deg, int n) {
    int i = blockIdx.x * blockDim.x + threadIdx.x;
    if (i < n) deg[i] = rsqrtf(deg[i]);
}

// ---------------- GEMM [n,64] @ [64,64] (+bias, optional relu) ----------------
// block = 256 threads = 4 rows x 64 cols. W staged in LDS once per block.
// xs[rl][k] is wave-uniform broadcast (free); Ws[k*64+c] is 2 lanes/bank (free).
__global__ void gemm64(const float* __restrict__ X, const float* __restrict__ W,
                       const float* __restrict__ bias, float* __restrict__ Y,
                       int n, int do_relu) {
    __shared__ float Ws[HDIM * HDIM];
    __shared__ float xs[4][HDIM];
    int tid = threadIdx.x;
    for (int i = tid; i < HDIM * HDIM; i += 256) Ws[i] = W[i];
    int c = tid & 63;
    int rl = tid >> 6;
    float bc = bias ? bias[c] : 0.0f;
    __syncthreads();
    for (int r0 = blockIdx.x * 4; r0 < n; r0 += gridDim.x * 4) {
        int r = r0 + rl;
        // each wave owns row rl of xs; no cross-wave sharing -> no barrier needed
        if (r < n) {
            xs[rl][c] = X[r * HDIM + c];
            float acc = bc;
#pragma unroll
            for (int k = 0; k < HDIM; ++k) acc += xs[rl][k] * Ws[k * HDIM + c];
            Y[r * HDIM + c] = do_relu ? fmaxf(acc, 0.0f) : acc;
        }
    }
}

// ---------------- self-loop init: agg = xw * dinv^2 ----------------
__global__ void selfloop_init(const float* __restrict__ xw, const float* __restrict__ dinv,
                              float* __restrict__ agg, int n) {
    int gidx = blockIdx.x * blockDim.x + threadIdx.x;
    if (gidx >= n * HDIM) return;
    int node = gidx >> 6;
    float di = dinv[node];
    agg[gidx] = xw[gidx] * di * di;
}

// ---------------- edge scatter for GCN conv ----------------
// one 64-lane group per edge; lane = channel
__global__ void scatter_conv(const float* __restrict__ xw, const int* __restrict__ src,
                             const int* __restrict__ dst, const float* __restrict__ dinv,
                             float* __restrict__ agg, int ne) {
    int gidx = blockIdx.x * blockDim.x + threadIdx.x;
    int e = gidx >> 6;
    if (e >= ne) return;
    int c = gidx & 63;
    int s = src[e], d = dst[e];
    float nrm = dinv[s] * dinv[d];
    atomicAdd(&agg[d * HDIM + c], xw[s * HDIM + c] * nrm);
}

// ---------------- edge scatter for residual: res[src] += adj * xw[dst] ----------------
__global__ void scatter_res(const float* __restrict__ xw, const int* __restrict__ src,
                            const int* __restrict__ dst, const float* __restrict__ adjv,
                            float* __restrict__ res, int ne) {
    int gidx = blockIdx.x * blockDim.x + threadIdx.x;
    int e = gidx >> 6;
    if (e >= ne) return;
    int c = gidx & 63;
    int s = src[e], d = dst[e];
    float av = adjv[e];
    atomicAdd(&res[s * HDIM + c], av * xw[d * HDIM + c]);
}

// ---------------- fused bias + LayerNorm + ReLU, one wave per node ----------------
__global__ void ln_relu(const float* __restrict__ agg, const float* __restrict__ cb,
                        const float* __restrict__ g, const float* __restrict__ b,
                        float* __restrict__ h, int n) {
    int gidx = blockIdx.x * blockDim.x + threadIdx.x;
    int node = gidx >> 6;
    if (node >= n) return;
    int c = gidx & 63;
    float v = agg[node * HDIM + c] + cb[c];
    float s = v;
#pragma unroll
    for (int off = 32; off; off >>= 1) s += __shfl_xor(s, off);
    float mu = s * (1.0f / 64.0f);
    float dv = v - mu;
    float q = dv * dv;
#pragma unroll
    for (int off = 32; off; off >>= 1) q += __shfl_xor(q, off);
    float var = q * (1.0f / 64.0f);
    float r = rsqrtf(var + 1e-5f);
    float o = dv * r * g[c] + b[c];
    h[node * HDIM + c] = fmaxf(o, 0.0f);
}

extern "C" void kernel_launch(void* const* d_in, const int* in_sizes, int n_in,
                              void* d_out, int out_size, void* d_ws, size_t ws_size,
                              hipStream_t stream) {
    const float* x     = (const float*)d_in[0];
    const float* xorg  = (const float*)d_in[1];
    const float* adjv  = (const float*)d_in[2];
    const float* Wi    = (const float*)d_in[3];
    const float* bi    = (const float*)d_in[4];
    const float* convW = (const float*)d_in[5];
    const float* convB = (const float*)d_in[6];
    const float* lng   = (const float*)d_in[7];
    const float* lnb   = (const float*)d_in[8];
    const float* Wl    = (const float*)d_in[9];
    const float* bl    = (const float*)d_in[10];
    const float* Wres  = (const float*)d_in[11];
    const int*   ei    = (const int*)d_in[12];
    const int* src = ei;
    const int* dst = ei + NEDGES;

    float* out = (float*)d_out;              // [N,64]
    float* res = out + NNODES * HDIM;        // [N,64]

    float* ws   = (float*)d_ws;
    float* h    = ws;                        // N*64
    float* xw   = ws + (size_t)NNODES * HDIM;     // N*64
    float* agg  = ws + (size_t)2 * NNODES * HDIM; // N*64
    float* dinv = ws + (size_t)3 * NNODES * HDIM; // N

    // residual accumulator must start at zero
    hipMemsetAsync(res, 0, (size_t)NNODES * HDIM * sizeof(float), stream);

    // degree^{-1/2} with self-loops (dst-side counts, PyG convention)
    deg_init<<<(NNODES + 255) / 256, 256, 0, stream>>>(dinv, NNODES);
    deg_count<<<(NEDGES + 255) / 256, 256, 0, stream>>>(dst, dinv, NEDGES);
    make_dinv<<<(NNODES + 255) / 256, 256, 0, stream>>>(dinv, NNODES);

    const int egrid = (int)(((long long)NEDGES * 64 + 255) / 256);
    const int ngrid = (NNODES * HDIM + 255) / 256;

    // h0 = relu(x @ Wi + bi)
    gemm64<<<2048, 256, 0, stream>>>(x, Wi, bi, h, NNODES, 1);

    // residual = scatter_src(adj * (x_org @ Wres)[dst])
    gemm64<<<2048, 256, 0, stream>>>(xorg, Wres, nullptr, xw, NNODES, 0);
    scatter_res<<<egrid, 256, 0, stream>>>(xw, src, dst, adjv, res, NEDGES);

    // 3 GCN layers
    for (int l = 0; l < 3; ++l) {
        gemm64<<<2048, 256, 0, stream>>>(h, convW + l * HDIM * HDIM, nullptr, xw, NNODES, 0);
        selfloop_init<<<ngrid, 256, 0, stream>>>(xw, dinv, agg, NNODES);
        scatter_conv<<<egrid, 256, 0, stream>>>(xw, src, dst, dinv, agg, NEDGES);
        ln_relu<<<ngrid, 256, 0, stream>>>(agg, convB + l * HDIM, lng + l * HDIM,
                                           lnb + l * HDIM, h, NNODES);
    }

    // out = h @ Wl + bl
    gemm64<<<2048, 256, 0, stream>>>(h, Wl, bl, out, NNODES, 0);
}

// Round 2
// 1094.952 us; speedup vs baseline: 1.6569x; 1.6569x over previous
//
#include <hip/hip_runtime.h>

#define NNODES 100000
#define NEDGES 1600000
#define HDIM 64
#define SCAN_BS 512
#define NBLK_SCAN ((NNODES + SCAN_BS - 1) / SCAN_BS)   // 196

// ---------------- CSR build: histogram ----------------
__global__ void hist_kernel(const int* __restrict__ src, const int* __restrict__ dst,
                            int* cnt_s, int* cnt_d, int ne) {
    int i = blockIdx.x * blockDim.x + threadIdx.x;
    if (i < ne) {
        atomicAdd(&cnt_d[dst[i]], 1);
        atomicAdd(&cnt_s[src[i]], 1);
    }
}

__global__ void make_dinv(const int* __restrict__ cnt_d, float* dinv, int n) {
    int i = blockIdx.x * blockDim.x + threadIdx.x;
    if (i < n) dinv[i] = rsqrtf((float)(cnt_d[i] + 1));   // +1 self-loop
}

// ---------------- CSR build: 2-level exclusive scan ----------------
__global__ void scan1(const int* __restrict__ cnt, int* rp, int* bsum, int n) {
    __shared__ int temp[SCAN_BS];
    int tid = threadIdx.x;
    int i = blockIdx.x * SCAN_BS + tid;
    int v = (i < n) ? cnt[i] : 0;
    temp[tid] = v;
    __syncthreads();
    for (int off = 1; off < SCAN_BS; off <<= 1) {
        int t = (tid >= off) ? temp[tid - off] : 0;
        __syncthreads();
        temp[tid] += t;
        __syncthreads();
    }
    int inc = temp[tid];
    if (i < n) rp[i] = inc - v;                 // block-local exclusive
    if (tid == SCAN_BS - 1) bsum[blockIdx.x] = inc;
}

__global__ void scan2(const int* __restrict__ bsum, int* boff, int nb) {
    __shared__ int temp[256];
    int tid = threadIdx.x;
    int v = (tid < nb) ? bsum[tid] : 0;
    temp[tid] = v;
    __syncthreads();
    for (int off = 1; off < 256; off <<= 1) {
        int t = (tid >= off) ? temp[tid - off] : 0;
        __syncthreads();
        temp[tid] += t;
        __syncthreads();
    }
    if (tid < nb) boff[tid] = temp[tid] - v;    // exclusive
}

// rp[i] += block offset; cursor = rp; rp[n] = total
__global__ void scan3(int* rp, int* cur, const int* __restrict__ boff, int n, int total) {
    int i = blockIdx.x * blockDim.x + threadIdx.x;
    if (i < n) {
        int v = rp[i] + boff[i / SCAN_BS];
        rp[i] = v;
        cur[i] = v;
    }
    if (i == 0) rp[n] = total;
}

// ---------------- CSR build: fill both CSRs ----------------
__global__ void fill_csr(const int* __restrict__ src, const int* __restrict__ dst,
                         const float* __restrict__ adjv,
                         int* cur_d, int* cur_s,
                         int* col_d, int* col_s, float* val_s, int ne) {
    int i = blockIdx.x * blockDim.x + threadIdx.x;
    if (i >= ne) return;
    int s = src[i], d = dst[i];
    int p = atomicAdd(&cur_d[d], 1);
    col_d[p] = s;
    int q = atomicAdd(&cur_s[s], 1);
    col_s[q] = d;
    val_s[q] = adjv[i];
}

// ---------------- GEMM [n,64] @ [64,64] (+bias, optional relu) ----------------
__global__ void gemm64(const float* __restrict__ X, const float* __restrict__ W,
                       const float* __restrict__ bias, float* __restrict__ Y,
                       int n, int do_relu) {
    __shared__ float Ws[HDIM * HDIM];
    __shared__ float xs[4][HDIM];
    int tid = threadIdx.x;
    for (int i = tid; i < HDIM * HDIM; i += 256) Ws[i] = W[i];
    int c = tid & 63;
    int rl = tid >> 6;
    float bc = bias ? bias[c] : 0.0f;
    __syncthreads();
    for (int r0 = blockIdx.x * 4; r0 < n; r0 += gridDim.x * 4) {
        int r = r0 + rl;
        if (r < n) {
            xs[rl][c] = X[r * HDIM + c];
            float acc = bc;
#pragma unroll
            for (int k = 0; k < HDIM; ++k) acc += xs[rl][k] * Ws[k * HDIM + c];
            Y[r * HDIM + c] = do_relu ? fmaxf(acc, 0.0f) : acc;
        }
    }
}

// ---------------- fused GCN gather + bias + LayerNorm + ReLU ----------------
// one wave per node; lane = channel; neighbor idx/norm prefetched 64-ahead
__global__ void conv_ln(const float* __restrict__ xw, const int* __restrict__ rp,
                        const int* __restrict__ cols, const float* __restrict__ dinv,
                        const float* __restrict__ cb, const float* __restrict__ g,
                        const float* __restrict__ b, float* __restrict__ h, int n) {
    int gid = blockIdx.x * blockDim.x + threadIdx.x;
    int node = gid >> 6;
    if (node >= n) return;
    int c = gid & 63;
    int e0 = rp[node], e1 = rp[node + 1];
    float di = dinv[node];
    float acc = xw[(size_t)node * HDIM + c] * di;   // self-loop (×di again below)
    for (int j0 = e0; j0 < e1; j0 += 64) {
        int jj = j0 + c;
        int sidx = 0;
        float dv = 0.0f;
        if (jj < e1) { sidx = cols[jj]; dv = dinv[sidx]; }
        int cnt = min(64, e1 - j0);
        for (int k = 0; k < cnt; ++k) {
            int sv = __shfl(sidx, k);
            float dvk = __shfl(dv, k);
            acc += xw[(size_t)sv * HDIM + c] * dvk;
        }
    }
    float v = acc * di + cb[c];
    // LayerNorm over 64 channels (wave-wide)
    float s = v;
#pragma unroll
    for (int off = 32; off; off >>= 1) s += __shfl_xor(s, off);
    float mu = s * (1.0f / 64.0f);
    float dvv = v - mu;
    float q = dvv * dvv;
#pragma unroll
    for (int off = 32; off; off >>= 1) q += __shfl_xor(q, off);
    float var = q * (1.0f / 64.0f);
    float r = rsqrtf(var + 1e-5f);
    float o = dvv * r * g[c] + b[c];
    h[(size_t)node * HDIM + c] = fmaxf(o, 0.0f);
}

// ---------------- residual gather: res[s] = sum_e adj[e] * xw[dst[e]] ----------------
__global__ void res_gather(const float* __restrict__ xw, const int* __restrict__ rp,
                           const int* __restrict__ cols, const float* __restrict__ vals,
                           float* __restrict__ res, int n) {
    int gid = blockIdx.x * blockDim.x + threadIdx.x;
    int node = gid >> 6;
    if (node >= n) return;
    int c = gid & 63;
    int e0 = rp[node], e1 = rp[node + 1];
    float acc = 0.0f;
    for (int j0 = e0; j0 < e1; j0 += 64) {
        int jj = j0 + c;
        int didx = 0;
        float vv = 0.0f;
        if (jj < e1) { didx = cols[jj]; vv = vals[jj]; }
        int cnt = min(64, e1 - j0);
        for (int k = 0; k < cnt; ++k) {
            int dv = __shfl(didx, k);
            float vk = __shfl(vv, k);
            acc += vk * xw[(size_t)dv * HDIM + c];
        }
    }
    res[(size_t)node * HDIM + c] = acc;
}

extern "C" void kernel_launch(void* const* d_in, const int* in_sizes, int n_in,
                              void* d_out, int out_size, void* d_ws, size_t ws_size,
                              hipStream_t stream) {
    const float* x     = (const float*)d_in[0];
    const float* xorg  = (const float*)d_in[1];
    const float* adjv  = (const float*)d_in[2];
    const float* Wi    = (const float*)d_in[3];
    const float* bi    = (const float*)d_in[4];
    const float* convW = (const float*)d_in[5];
    const float* convB = (const float*)d_in[6];
    const float* lng   = (const float*)d_in[7];
    const float* lnb   = (const float*)d_in[8];
    const float* Wl    = (const float*)d_in[9];
    const float* bl    = (const float*)d_in[10];
    const float* Wres  = (const float*)d_in[11];
    const int*   ei    = (const int*)d_in[12];
    const int* src = ei;
    const int* dst = ei + NEDGES;

    float* out = (float*)d_out;               // [N,64]
    float* res = out + (size_t)NNODES * HDIM; // [N,64]

    // ---- workspace layout ----
    float* h    = (float*)d_ws;                        // N*64
    float* xw   = h + (size_t)NNODES * HDIM;           // N*64
    float* dinv = xw + (size_t)NNODES * HDIM;          // N
    int* cnt_d  = (int*)(dinv + NNODES);               // N
    int* cnt_s  = cnt_d + NNODES;                      // N
    int* rp_d   = cnt_s + NNODES;                      // N+1
    int* rp_s   = rp_d + (NNODES + 1);                 // N+1
    int* cur_d  = rp_s + (NNODES + 1);                 // N
    int* cur_s  = cur_d + NNODES;                      // N
    int* col_d  = cur_s + NNODES;                      // E
    int* col_s  = col_d + NEDGES;                      // E
    float* val_s = (float*)(col_s + NEDGES);           // E
    int* bsum_d = (int*)(val_s + NEDGES);              // 256
    int* boff_d = bsum_d + 256;                        // 256
    int* bsum_s = boff_d + 256;                        // 256
    int* boff_s = bsum_s + 256;                        // 256

    const int ngrid1 = (NNODES + 255) / 256;
    const int egrid1 = (NEDGES + 255) / 256;
    const int ngrid64 = (NNODES * HDIM + 255) / 256;

    // ---- CSR build ----
    hipMemsetAsync(cnt_d, 0, 2 * (size_t)NNODES * sizeof(int), stream);
    hist_kernel<<<egrid1, 256, 0, stream>>>(src, dst, cnt_s, cnt_d, NEDGES);
    make_dinv<<<ngrid1, 256, 0, stream>>>(cnt_d, dinv, NNODES);

    scan1<<<NBLK_SCAN, SCAN_BS, 0, stream>>>(cnt_d, rp_d, bsum_d, NNODES);
    scan1<<<NBLK_SCAN, SCAN_BS, 0, stream>>>(cnt_s, rp_s, bsum_s, NNODES);
    scan2<<<1, 256, 0, stream>>>(bsum_d, boff_d, NBLK_SCAN);
    scan2<<<1, 256, 0, stream>>>(bsum_s, boff_s, NBLK_SCAN);
    scan3<<<ngrid1, 256, 0, stream>>>(rp_d, cur_d, boff_d, NNODES, NEDGES);
    scan3<<<ngrid1, 256, 0, stream>>>(rp_s, cur_s, boff_s, NNODES, NEDGES);
    fill_csr<<<egrid1, 256, 0, stream>>>(src, dst, adjv, cur_d, cur_s,
                                         col_d, col_s, val_s, NEDGES);

    // ---- h0 = relu(x @ Wi + bi) ----
    gemm64<<<2048, 256, 0, stream>>>(x, Wi, bi, h, NNODES, 1);

    // ---- residual = gather_src(adj * (x_org @ Wres)[dst]) ----
    gemm64<<<2048, 256, 0, stream>>>(xorg, Wres, nullptr, xw, NNODES, 0);
    res_gather<<<ngrid64, 256, 0, stream>>>(xw, rp_s, col_s, val_s, res, NNODES);

    // ---- 3 GCN layers: gemm -> fused gather+LN+ReLU ----
    for (int l = 0; l < 3; ++l) {
        gemm64<<<2048, 256, 0, stream>>>(h, convW + l * HDIM * HDIM, nullptr, xw, NNODES, 0);
        conv_ln<<<ngrid64, 256, 0, stream>>>(xw, rp_d, col_d, dinv,
                                             convB + l * HDIM, lng + l * HDIM,
                                             lnb + l * HDIM, h, NNODES);
    }

    // ---- out = h @ Wl + bl ----
    gemm64<<<2048, 256, 0, stream>>>(h, Wl, bl, out, NNODES, 0);
}

// Round 3
// 874.797 us; speedup vs baseline: 2.0738x; 1.2517x over previous
//
#include <hip/hip_runtime.h>

#define NNODES 100000
#define NEDGES 1600000
#define HDIM 64
#define SCAN_BS 512
#define NBLK_SCAN ((NNODES + SCAN_BS - 1) / SCAN_BS)   // 196

// ---------- bf16x2 pack/unpack (RNE pack; exact unpack) ----------
__device__ inline unsigned pack_bf16x2(float a, float b) {
    union { float f; unsigned u; } ua, ub;
    ua.f = a; ub.f = b;
    unsigned ra = (ua.u + 0x7FFFu + ((ua.u >> 16) & 1u)) >> 16;
    unsigned rb = (ub.u + 0x7FFFu + ((ub.u >> 16) & 1u)) >> 16;
    return ra | (rb << 16);
}
__device__ inline float2 unpack_bf16x2(unsigned p) {
    union { unsigned u; float f; } a, b;
    a.u = p << 16;
    b.u = p & 0xFFFF0000u;
    return make_float2(a.f, b.f);
}

// ---------------- CSR build: histogram (4 edges/thread) ----------------
__global__ void hist4(const int4* __restrict__ src4, const int4* __restrict__ dst4,
                      int* cnt_s, int* cnt_d, int ne4) {
    int i = blockIdx.x * blockDim.x + threadIdx.x;
    if (i >= ne4) return;
    int4 s = src4[i], d = dst4[i];
    atomicAdd(&cnt_s[s.x], 1); atomicAdd(&cnt_s[s.y], 1);
    atomicAdd(&cnt_s[s.z], 1); atomicAdd(&cnt_s[s.w], 1);
    atomicAdd(&cnt_d[d.x], 1); atomicAdd(&cnt_d[d.y], 1);
    atomicAdd(&cnt_d[d.z], 1); atomicAdd(&cnt_d[d.w], 1);
}

__global__ void make_dinv(const int* __restrict__ cnt_d, float* dinv, int n) {
    int i = blockIdx.x * blockDim.x + threadIdx.x;
    if (i < n) dinv[i] = rsqrtf((float)(cnt_d[i] + 1));   // +1 self-loop
}

// ---------------- CSR build: 2-level exclusive scan ----------------
__global__ void scan1(const int* __restrict__ cnt, int* rp, int* bsum, int n) {
    __shared__ int temp[SCAN_BS];
    int tid = threadIdx.x;
    int i = blockIdx.x * SCAN_BS + tid;
    int v = (i < n) ? cnt[i] : 0;
    temp[tid] = v;
    __syncthreads();
    for (int off = 1; off < SCAN_BS; off <<= 1) {
        int t = (tid >= off) ? temp[tid - off] : 0;
        __syncthreads();
        temp[tid] += t;
        __syncthreads();
    }
    int inc = temp[tid];
    if (i < n) rp[i] = inc - v;
    if (tid == SCAN_BS - 1) bsum[blockIdx.x] = inc;
}

__global__ void scan2(const int* __restrict__ bsum, int* boff, int nb) {
    __shared__ int temp[256];
    int tid = threadIdx.x;
    int v = (tid < nb) ? bsum[tid] : 0;
    temp[tid] = v;
    __syncthreads();
    for (int off = 1; off < 256; off <<= 1) {
        int t = (tid >= off) ? temp[tid - off] : 0;
        __syncthreads();
        temp[tid] += t;
        __syncthreads();
    }
    if (tid < nb) boff[tid] = temp[tid] - v;
}

__global__ void scan3(int* rp, int* cur, const int* __restrict__ boff, int n, int total) {
    int i = blockIdx.x * blockDim.x + threadIdx.x;
    if (i < n) {
        int v = rp[i] + boff[i / SCAN_BS];
        rp[i] = v;
        cur[i] = v;
    }
    if (i == 0) rp[n] = total;
}

// ---------------- CSR fill: one packed 8B payload per CSR ----------------
// dst-CSR payload: (src, dinv[src]);  src-CSR payload: (dst, adjv)
__global__ void fill_csr(const int* __restrict__ src, const int* __restrict__ dst,
                         const float* __restrict__ adjv, const float* __restrict__ dinv,
                         int* cur_d, int* cur_s,
                         int2* __restrict__ csr_d, int2* __restrict__ csr_s, int ne) {
    int i = blockIdx.x * blockDim.x + threadIdx.x;
    if (i >= ne) return;
    int s = src[i], d = dst[i];
    int2 pd; pd.x = s; pd.y = __float_as_int(dinv[s]);
    int p = atomicAdd(&cur_d[d], 1);
    csr_d[p] = pd;
    int2 ps; ps.x = d; ps.y = __float_as_int(adjv[i]);
    int q = atomicAdd(&cur_s[s], 1);
    csr_s[q] = ps;
}

// ---------------- GEMM [n,64]@[64,64] -> f32 out (+bias, optional relu) ----------------
__global__ void gemm64(const float* __restrict__ X, const float* __restrict__ W,
                       const float* __restrict__ bias, float* __restrict__ Y,
                       int n, int do_relu) {
    __shared__ float Ws[HDIM * HDIM];
    __shared__ float xs[4][HDIM];
    int tid = threadIdx.x;
    for (int i = tid; i < HDIM * HDIM; i += 256) Ws[i] = W[i];
    int c = tid & 63;
    int rl = tid >> 6;
    float bc = bias ? bias[c] : 0.0f;
    __syncthreads();
    for (int r0 = blockIdx.x * 4; r0 < n; r0 += gridDim.x * 4) {
        int r = r0 + rl;
        if (r < n) {
            xs[rl][c] = X[r * HDIM + c];
            float acc = bc;
#pragma unroll
            for (int k = 0; k < HDIM; ++k) acc += xs[rl][k] * Ws[k * HDIM + c];
            Y[r * HDIM + c] = do_relu ? fmaxf(acc, 0.0f) : acc;
        }
    }
}

// ---------------- GEMM [n,64]@[64,64] -> packed bf16x2 out ----------------
// 256 thr = 8 rows x 32 pairs; each thread computes channels 2p, 2p+1
__global__ void gemm64p(const float* __restrict__ X, const float* __restrict__ W,
                        unsigned* __restrict__ Yp, int n) {
    __shared__ float Ws[HDIM * HDIM];
    __shared__ float xs[8][HDIM];
    int tid = threadIdx.x;
    for (int i = tid; i < HDIM * HDIM; i += 256) Ws[i] = W[i];
    int pr = tid & 31;
    int rl = tid >> 5;
    __syncthreads();
    const float2* X2 = (const float2*)X;
    for (int r0 = blockIdx.x * 8; r0 < n; r0 += gridDim.x * 8) {
        int r = r0 + rl;
        if (r < n) {
            float2 xv = X2[(size_t)r * 32 + pr];
            xs[rl][2 * pr] = xv.x;
            xs[rl][2 * pr + 1] = xv.y;
            float acc0 = 0.0f, acc1 = 0.0f;
#pragma unroll
            for (int k = 0; k < HDIM; ++k) {
                float xk = xs[rl][k];
                acc0 += xk * Ws[k * HDIM + 2 * pr];
                acc1 += xk * Ws[k * HDIM + 2 * pr + 1];
            }
            Yp[(size_t)r * 32 + pr] = pack_bf16x2(acc0, acc1);
        }
    }
}

// ---------------- fused GCN gather + bias + LN + ReLU ----------------
// half-wave (32 lanes) per node; each lane holds 2 packed channels
__global__ void conv_ln(const unsigned* __restrict__ xwp, const int* __restrict__ rp,
                        const int2* __restrict__ csr, const float* __restrict__ dinv,
                        const float* __restrict__ cb, const float* __restrict__ g,
                        const float* __restrict__ b, float* __restrict__ h, int n) {
    int gid = blockIdx.x * blockDim.x + threadIdx.x;
    int node = gid >> 5;
    if (node >= n) return;
    int c2 = gid & 31;                       // channel pair
    int wl = threadIdx.x & 63;               // lane in wave
    int hb = wl & 32;                        // half base (0 or 32)
    int e0 = rp[node], e1 = rp[node + 1];
    float di = dinv[node];
    float2 self = unpack_bf16x2(xwp[(size_t)node * 32 + c2]);
    float acc0 = self.x * di, acc1 = self.y * di;
    for (int j0 = e0; j0 < e1; j0 += 32) {
        int jj = j0 + c2;
        int sidx = 0; float dv = 0.0f;
        if (jj < e1) { int2 pl = csr[jj]; sidx = pl.x; dv = __int_as_float(pl.y); }
        int cnt = min(32, e1 - j0);
        for (int k = 0; k < cnt; ++k) {
            int sv = __shfl(sidx, hb | k);
            float dvk = __shfl(dv, hb | k);
            float2 xv = unpack_bf16x2(xwp[(size_t)sv * 32 + c2]);
            acc0 += xv.x * dvk;
            acc1 += xv.y * dvk;
        }
    }
    float v0 = acc0 * di + cb[2 * c2];
    float v1 = acc1 * di + cb[2 * c2 + 1];
    // LayerNorm over 64 channels (32 lanes x 2)
    float s = v0 + v1;
#pragma unroll
    for (int off = 16; off; off >>= 1) s += __shfl_xor(s, off);
    float mu = s * (1.0f / 64.0f);
    float d0 = v0 - mu, d1 = v1 - mu;
    float q = d0 * d0 + d1 * d1;
#pragma unroll
    for (int off = 16; off; off >>= 1) q += __shfl_xor(q, off);
    float r = rsqrtf(q * (1.0f / 64.0f) + 1e-5f);
    float o0 = fmaxf(d0 * r * g[2 * c2] + b[2 * c2], 0.0f);
    float o1 = fmaxf(d1 * r * g[2 * c2 + 1] + b[2 * c2 + 1], 0.0f);
    *(float2*)&h[(size_t)node * HDIM + 2 * c2] = make_float2(o0, o1);
}

// ---------------- residual gather: res[s] = sum adj * xw[dst] ----------------
__global__ void res_gather(const unsigned* __restrict__ xwp, const int* __restrict__ rp,
                           const int2* __restrict__ csr, float* __restrict__ res, int n) {
    int gid = blockIdx.x * blockDim.x + threadIdx.x;
    int node = gid >> 5;
    if (node >= n) return;
    int c2 = gid & 31;
    int wl = threadIdx.x & 63;
    int hb = wl & 32;
    int e0 = rp[node], e1 = rp[node + 1];
    float acc0 = 0.0f, acc1 = 0.0f;
    for (int j0 = e0; j0 < e1; j0 += 32) {
        int jj = j0 + c2;
        int didx = 0; float vv = 0.0f;
        if (jj < e1) { int2 pl = csr[jj]; didx = pl.x; vv = __int_as_float(pl.y); }
        int cnt = min(32, e1 - j0);
        for (int k = 0; k < cnt; ++k) {
            int dv = __shfl(didx, hb | k);
            float vk = __shfl(vv, hb | k);
            float2 xv = unpack_bf16x2(xwp[(size_t)dv * 32 + c2]);
            acc0 += vk * xv.x;
            acc1 += vk * xv.y;
        }
    }
    *(float2*)&res[(size_t)node * HDIM + 2 * c2] = make_float2(acc0, acc1);
}

extern "C" void kernel_launch(void* const* d_in, const int* in_sizes, int n_in,
                              void* d_out, int out_size, void* d_ws, size_t ws_size,
                              hipStream_t stream) {
    const float* x     = (const float*)d_in[0];
    const float* xorg  = (const float*)d_in[1];
    const float* adjv  = (const float*)d_in[2];
    const float* Wi    = (const float*)d_in[3];
    const float* bi    = (const float*)d_in[4];
    const float* convW = (const float*)d_in[5];
    const float* convB = (const float*)d_in[6];
    const float* lng   = (const float*)d_in[7];
    const float* lnb   = (const float*)d_in[8];
    const float* Wl    = (const float*)d_in[9];
    const float* bl    = (const float*)d_in[10];
    const float* Wres  = (const float*)d_in[11];
    const int*   ei    = (const int*)d_in[12];
    const int* src = ei;
    const int* dst = ei + NEDGES;

    float* out = (float*)d_out;               // [N,64]
    float* res = out + (size_t)NNODES * HDIM; // [N,64]

    // ---- workspace layout ----
    float* h      = (float*)d_ws;                       // N*64 f32
    unsigned* xwp = (unsigned*)(h + (size_t)NNODES * HDIM); // N*32 u32
    float* dinv   = (float*)(xwp + (size_t)NNODES * 32);    // N
    int* cnt_d    = (int*)(dinv + NNODES);              // N
    int* cnt_s    = cnt_d + NNODES;                     // N
    int* rp_d     = cnt_s + NNODES;                     // N+1
    int* rp_s     = rp_d + (NNODES + 1);                // N+1
    int* cur_d    = rp_s + (NNODES + 1);                // N
    int* cur_s    = cur_d + NNODES;                     // N
    int* bsum_d   = cur_s + NNODES;                     // 256
    int* boff_d   = bsum_d + 256;                       // 256
    int* bsum_s   = boff_d + 256;                       // 256
    int* boff_s   = bsum_s + 256;                       // 256
    // int2 arrays 8B-aligned
    size_t ofs = (size_t)(boff_s + 256 - (int*)d_ws);
    ofs = (ofs + 1) & ~(size_t)1;
    int2* csr_d = (int2*)((int*)d_ws + ofs);            // E int2
    int2* csr_s = csr_d + NEDGES;                       // E int2

    const int ngrid1 = (NNODES + 255) / 256;
    const int egrid1 = (NEDGES + 255) / 256;
    const int ngrid32 = (NNODES * 32 + 255) / 256;

    // ---- CSR build ----
    hipMemsetAsync(cnt_d, 0, 2 * (size_t)NNODES * sizeof(int), stream);
    hist4<<<(NEDGES / 4 + 255) / 256, 256, 0, stream>>>(
        (const int4*)src, (const int4*)dst, cnt_s, cnt_d, NEDGES / 4);
    make_dinv<<<ngrid1, 256, 0, stream>>>(cnt_d, dinv, NNODES);

    scan1<<<NBLK_SCAN, SCAN_BS, 0, stream>>>(cnt_d, rp_d, bsum_d, NNODES);
    scan1<<<NBLK_SCAN, SCAN_BS, 0, stream>>>(cnt_s, rp_s, bsum_s, NNODES);
    scan2<<<1, 256, 0, stream>>>(bsum_d, boff_d, NBLK_SCAN);
    scan2<<<1, 256, 0, stream>>>(bsum_s, boff_s, NBLK_SCAN);
    scan3<<<ngrid1, 256, 0, stream>>>(rp_d, cur_d, boff_d, NNODES, NEDGES);
    scan3<<<ngrid1, 256, 0, stream>>>(rp_s, cur_s, boff_s, NNODES, NEDGES);
    fill_csr<<<egrid1, 256, 0, stream>>>(src, dst, adjv, dinv, cur_d, cur_s,
                                         csr_d, csr_s, NEDGES);

    // ---- h0 = relu(x @ Wi + bi) ----
    gemm64<<<2048, 256, 0, stream>>>(x, Wi, bi, h, NNODES, 1);

    // ---- residual = gather_src(adj * (x_org @ Wres)[dst]) ----
    gemm64p<<<2048, 256, 0, stream>>>(xorg, Wres, xwp, NNODES);
    res_gather<<<ngrid32, 256, 0, stream>>>(xwp, rp_s, csr_s, res, NNODES);

    // ---- 3 GCN layers: packed gemm -> fused gather+LN+ReLU ----
    for (int l = 0; l < 3; ++l) {
        gemm64p<<<2048, 256, 0, stream>>>(h, convW + l * HDIM * HDIM, xwp, NNODES);
        conv_ln<<<ngrid32, 256, 0, stream>>>(xwp, rp_d, csr_d, dinv,
                                             convB + l * HDIM, lng + l * HDIM,
                                             lnb + l * HDIM, h, NNODES);
    }

    // ---- out = h @ Wl + bl ----
    gemm64<<<2048, 256, 0, stream>>>(h, Wl, bl, out, NNODES, 0);
}

// Round 4
// 768.364 us; speedup vs baseline: 2.3611x; 1.1385x over previous
//
#include <hip/hip_runtime.h>

#define NNODES 100000
#define NEDGES 1600000
#define HDIM 64
#define SCAN_BS 512
#define NBLK_SCAN ((NNODES + SCAN_BS - 1) / SCAN_BS)   // 196
#define NPART 8
#define PRANGE 12500   // NNODES / NPART exactly

// ---------- bf16x2 pack/unpack (RNE pack; exact unpack) ----------
__device__ inline unsigned pack_bf16x2(float a, float b) {
    union { float f; unsigned u; } ua, ub;
    ua.f = a; ub.f = b;
    unsigned ra = (ua.u + 0x7FFFu + ((ua.u >> 16) & 1u)) >> 16;
    unsigned rb = (ub.u + 0x7FFFu + ((ub.u >> 16) & 1u)) >> 16;
    return ra | (rb << 16);
}
__device__ inline float2 unpack_bf16x2(unsigned p) {
    union { unsigned u; float f; } a, b;
    a.u = p << 16;
    b.u = p & 0xFFFF0000u;
    return make_float2(a.f, b.f);
}

// ---------------- CSR build: histogram (4 edges/thread) ----------------
__global__ void hist4(const int4* __restrict__ src4, const int4* __restrict__ dst4,
                      int* cnt_s, int* cnt_d, int ne4) {
    int i = blockIdx.x * blockDim.x + threadIdx.x;
    if (i >= ne4) return;
    int4 s = src4[i], d = dst4[i];
    atomicAdd(&cnt_s[s.x], 1); atomicAdd(&cnt_s[s.y], 1);
    atomicAdd(&cnt_s[s.z], 1); atomicAdd(&cnt_s[s.w], 1);
    atomicAdd(&cnt_d[d.x], 1); atomicAdd(&cnt_d[d.y], 1);
    atomicAdd(&cnt_d[d.z], 1); atomicAdd(&cnt_d[d.w], 1);
}

__global__ void make_dinv(const int* __restrict__ cnt_d, float* dinv, int n) {
    int i = blockIdx.x * blockDim.x + threadIdx.x;
    if (i < n) dinv[i] = rsqrtf((float)(cnt_d[i] + 1));   // +1 self-loop
}

// ---------------- CSR build: 2-level exclusive scan ----------------
__global__ void scan1(const int* __restrict__ cnt, int* rp, int* bsum, int n) {
    __shared__ int temp[SCAN_BS];
    int tid = threadIdx.x;
    int i = blockIdx.x * SCAN_BS + tid;
    int v = (i < n) ? cnt[i] : 0;
    temp[tid] = v;
    __syncthreads();
    for (int off = 1; off < SCAN_BS; off <<= 1) {
        int t = (tid >= off) ? temp[tid - off] : 0;
        __syncthreads();
        temp[tid] += t;
        __syncthreads();
    }
    int inc = temp[tid];
    if (i < n) rp[i] = inc - v;
    if (tid == SCAN_BS - 1) bsum[blockIdx.x] = inc;
}

__global__ void scan2(const int* __restrict__ bsum, int* boff, int nb) {
    __shared__ int temp[256];
    int tid = threadIdx.x;
    int v = (tid < nb) ? bsum[tid] : 0;
    temp[tid] = v;
    __syncthreads();
    for (int off = 1; off < 256; off <<= 1) {
        int t = (tid >= off) ? temp[tid - off] : 0;
        __syncthreads();
        temp[tid] += t;
        __syncthreads();
    }
    if (tid < nb) boff[tid] = temp[tid] - v;
}

__global__ void scan3(int* rp, int* cur, const int* __restrict__ boff, int n, int total) {
    int i = blockIdx.x * blockDim.x + threadIdx.x;
    if (i < n) {
        int v = rp[i] + boff[i / SCAN_BS];
        rp[i] = v;
        cur[i] = v;
    }
    if (i == 0) rp[n] = total;
}

// ---------------- CSR fill, XCD-partitioned scatter ----------------
// blockIdx&7 -> XCD (default round-robin dispatch); each part owns an exclusive
// node range so its CSR region (~1.6 MB) is written by one XCD only -> lines
// complete in that XCD's L2 and write back once.
// dst-CSR payload: (src, dinv[src]);  src-CSR payload: (dst, adjv)
__global__ void fill_csr_part(const int* __restrict__ src, const int* __restrict__ dst,
                              const float* __restrict__ adjv, const float* __restrict__ dinv,
                              int* cur_d, int* cur_s,
                              int2* __restrict__ csr_d, int2* __restrict__ csr_s, int ne) {
    int part = blockIdx.x & (NPART - 1);
    int blk  = blockIdx.x >> 3;
    int nblk = gridDim.x >> 3;
    int lo = part * PRANGE;
    for (int i = blk * blockDim.x + threadIdx.x; i < ne; i += nblk * blockDim.x) {
        int s = src[i], d = dst[i];
        if ((unsigned)(d - lo) < PRANGE) {
            int2 pd; pd.x = s; pd.y = __float_as_int(dinv[s]);
            int p = atomicAdd(&cur_d[d], 1);
            csr_d[p] = pd;
        }
        if ((unsigned)(s - lo) < PRANGE) {
            int2 ps; ps.x = d; ps.y = __float_as_int(adjv[i]);
            int q = atomicAdd(&cur_s[s], 1);
            csr_s[q] = ps;
        }
    }
}

// ---------------- GEMM [n,64]@[64,64] -> f32 out (+bias, optional relu) ----------------
__global__ void gemm64(const float* __restrict__ X, const float* __restrict__ W,
                       const float* __restrict__ bias, float* __restrict__ Y,
                       int n, int do_relu) {
    __shared__ float Ws[HDIM * HDIM];
    __shared__ float xs[4][HDIM];
    int tid = threadIdx.x;
    for (int i = tid; i < HDIM * HDIM; i += 256) Ws[i] = W[i];
    int c = tid & 63;
    int rl = tid >> 6;
    float bc = bias ? bias[c] : 0.0f;
    __syncthreads();
    for (int r0 = blockIdx.x * 4; r0 < n; r0 += gridDim.x * 4) {
        int r = r0 + rl;
        if (r < n) {
            xs[rl][c] = X[r * HDIM + c];
            float acc = bc;
#pragma unroll
            for (int k = 0; k < HDIM; ++k) acc += xs[rl][k] * Ws[k * HDIM + c];
            Y[r * HDIM + c] = do_relu ? fmaxf(acc, 0.0f) : acc;
        }
    }
}

// ---------------- GEMM [n,64]@[64,64] -> packed bf16x2 out ----------------
__global__ void gemm64p(const float* __restrict__ X, const float* __restrict__ W,
                        unsigned* __restrict__ Yp, int n) {
    __shared__ float Ws[HDIM * HDIM];
    __shared__ float xs[8][HDIM];
    int tid = threadIdx.x;
    for (int i = tid; i < HDIM * HDIM; i += 256) Ws[i] = W[i];
    int pr = tid & 31;
    int rl = tid >> 5;
    __syncthreads();
    const float2* X2 = (const float2*)X;
    for (int r0 = blockIdx.x * 8; r0 < n; r0 += gridDim.x * 8) {
        int r = r0 + rl;
        if (r < n) {
            float2 xv = X2[(size_t)r * 32 + pr];
            xs[rl][2 * pr] = xv.x;
            xs[rl][2 * pr + 1] = xv.y;
            float acc0 = 0.0f, acc1 = 0.0f;
#pragma unroll
            for (int k = 0; k < HDIM; ++k) {
                float xk = xs[rl][k];
                acc0 += xk * Ws[k * HDIM + 2 * pr];
                acc1 += xk * Ws[k * HDIM + 2 * pr + 1];
            }
            Yp[(size_t)r * 32 + pr] = pack_bf16x2(acc0, acc1);
        }
    }
}

// ---------------- fused GCN gather + bias + LN + ReLU ----------------
// half-wave (32 lanes) per node; each lane holds 2 packed channels
__global__ void conv_ln(const unsigned* __restrict__ xwp, const int* __restrict__ rp,
                        const int2* __restrict__ csr, const float* __restrict__ dinv,
                        const float* __restrict__ cb, const float* __restrict__ g,
                        const float* __restrict__ b, float* __restrict__ h, int n) {
    int gid = blockIdx.x * blockDim.x + threadIdx.x;
    int node = gid >> 5;
    if (node >= n) return;
    int c2 = gid & 31;                       // channel pair
    int wl = threadIdx.x & 63;               // lane in wave
    int hb = wl & 32;                        // half base (0 or 32)
    int e0 = rp[node], e1 = rp[node + 1];
    float di = dinv[node];
    float2 self = unpack_bf16x2(xwp[(size_t)node * 32 + c2]);
    float acc0 = self.x * di, acc1 = self.y * di;
    for (int j0 = e0; j0 < e1; j0 += 32) {
        int jj = j0 + c2;
        int sidx = 0; float dv = 0.0f;
        if (jj < e1) { int2 pl = csr[jj]; sidx = pl.x; dv = __int_as_float(pl.y); }
        int cnt = min(32, e1 - j0);
        for (int k = 0; k < cnt; ++k) {
            int sv = __shfl(sidx, hb | k);
            float dvk = __shfl(dv, hb | k);
            float2 xv = unpack_bf16x2(xwp[(size_t)sv * 32 + c2]);
            acc0 += xv.x * dvk;
            acc1 += xv.y * dvk;
        }
    }
    float v0 = acc0 * di + cb[2 * c2];
    float v1 = acc1 * di + cb[2 * c2 + 1];
    // LayerNorm over 64 channels (32 lanes x 2)
    float s = v0 + v1;
#pragma unroll
    for (int off = 16; off; off >>= 1) s += __shfl_xor(s, off);
    float mu = s * (1.0f / 64.0f);
    float d0 = v0 - mu, d1 = v1 - mu;
    float q = d0 * d0 + d1 * d1;
#pragma unroll
    for (int off = 16; off; off >>= 1) q += __shfl_xor(q, off);
    float r = rsqrtf(q * (1.0f / 64.0f) + 1e-5f);
    float o0 = fmaxf(d0 * r * g[2 * c2] + b[2 * c2], 0.0f);
    float o1 = fmaxf(d1 * r * g[2 * c2 + 1] + b[2 * c2 + 1], 0.0f);
    *(float2*)&h[(size_t)node * HDIM + 2 * c2] = make_float2(o0, o1);
}

// ---------------- residual gather: res[s] = sum adj * xw[dst] ----------------
__global__ void res_gather(const unsigned* __restrict__ xwp, const int* __restrict__ rp,
                           const int2* __restrict__ csr, float* __restrict__ res, int n) {
    int gid = blockIdx.x * blockDim.x + threadIdx.x;
    int node = gid >> 5;
    if (node >= n) return;
    int c2 = gid & 31;
    int wl = threadIdx.x & 63;
    int hb = wl & 32;
    int e0 = rp[node], e1 = rp[node + 1];
    float acc0 = 0.0f, acc1 = 0.0f;
    for (int j0 = e0; j0 < e1; j0 += 32) {
        int jj = j0 + c2;
        int didx = 0; float vv = 0.0f;
        if (jj < e1) { int2 pl = csr[jj]; didx = pl.x; vv = __int_as_float(pl.y); }
        int cnt = min(32, e1 - j0);
        for (int k = 0; k < cnt; ++k) {
            int dv = __shfl(didx, hb | k);
            float vk = __shfl(vv, hb | k);
            float2 xv = unpack_bf16x2(xwp[(size_t)dv * 32 + c2]);
            acc0 += vk * xv.x;
            acc1 += vk * xv.y;
        }
    }
    *(float2*)&res[(size_t)node * HDIM + 2 * c2] = make_float2(acc0, acc1);
}

extern "C" void kernel_launch(void* const* d_in, const int* in_sizes, int n_in,
                              void* d_out, int out_size, void* d_ws, size_t ws_size,
                              hipStream_t stream) {
    const float* x     = (const float*)d_in[0];
    const float* xorg  = (const float*)d_in[1];
    const float* adjv  = (const float*)d_in[2];
    const float* Wi    = (const float*)d_in[3];
    const float* bi    = (const float*)d_in[4];
    const float* convW = (const float*)d_in[5];
    const float* convB = (const float*)d_in[6];
    const float* lng   = (const float*)d_in[7];
    const float* lnb   = (const float*)d_in[8];
    const float* Wl    = (const float*)d_in[9];
    const float* bl    = (const float*)d_in[10];
    const float* Wres  = (const float*)d_in[11];
    const int*   ei    = (const int*)d_in[12];
    const int* src = ei;
    const int* dst = ei + NEDGES;

    float* out = (float*)d_out;               // [N,64]
    float* res = out + (size_t)NNODES * HDIM; // [N,64]

    // ---- workspace layout ----
    float* h      = (float*)d_ws;                       // N*64 f32
    unsigned* xwp = (unsigned*)(h + (size_t)NNODES * HDIM); // N*32 u32
    float* dinv   = (float*)(xwp + (size_t)NNODES * 32);    // N
    int* cnt_d    = (int*)(dinv + NNODES);              // N
    int* cnt_s    = cnt_d + NNODES;                     // N
    int* rp_d     = cnt_s + NNODES;                     // N+1
    int* rp_s     = rp_d + (NNODES + 1);                // N+1
    int* cur_d    = rp_s + (NNODES + 1);                // N
    int* cur_s    = cur_d + NNODES;                     // N
    int* bsum_d   = cur_s + NNODES;                     // 256
    int* boff_d   = bsum_d + 256;                       // 256
    int* bsum_s   = boff_d + 256;                       // 256
    int* boff_s   = bsum_s + 256;                       // 256
    size_t ofs = (size_t)(boff_s + 256 - (int*)d_ws);
    ofs = (ofs + 1) & ~(size_t)1;
    int2* csr_d = (int2*)((int*)d_ws + ofs);            // E int2
    int2* csr_s = csr_d + NEDGES;                       // E int2

    const int ngrid1 = (NNODES + 255) / 256;
    const int ngrid32 = (NNODES * 32 + 255) / 256;

    // ---- CSR build ----
    hipMemsetAsync(cnt_d, 0, 2 * (size_t)NNODES * sizeof(int), stream);
    hist4<<<(NEDGES / 4 + 255) / 256, 256, 0, stream>>>(
        (const int4*)src, (const int4*)dst, cnt_s, cnt_d, NEDGES / 4);
    make_dinv<<<ngrid1, 256, 0, stream>>>(cnt_d, dinv, NNODES);

    scan1<<<NBLK_SCAN, SCAN_BS, 0, stream>>>(cnt_d, rp_d, bsum_d, NNODES);
    scan1<<<NBLK_SCAN, SCAN_BS, 0, stream>>>(cnt_s, rp_s, bsum_s, NNODES);
    scan2<<<1, 256, 0, stream>>>(bsum_d, boff_d, NBLK_SCAN);
    scan2<<<1, 256, 0, stream>>>(bsum_s, boff_s, NBLK_SCAN);
    scan3<<<ngrid1, 256, 0, stream>>>(rp_d, cur_d, boff_d, NNODES, NEDGES);
    scan3<<<ngrid1, 256, 0, stream>>>(rp_s, cur_s, boff_s, NNODES, NEDGES);
    // 2048 blocks = 8 parts x 256 blocks; part = blockIdx&7 -> XCD round-robin
    fill_csr_part<<<2048, 256, 0, stream>>>(src, dst, adjv, dinv, cur_d, cur_s,
                                            csr_d, csr_s, NEDGES);

    // ---- h0 = relu(x @ Wi + bi) ----
    gemm64<<<2048, 256, 0, stream>>>(x, Wi, bi, h, NNODES, 1);

    // ---- residual = gather_src(adj * (x_org @ Wres)[dst]) ----
    gemm64p<<<2048, 256, 0, stream>>>(xorg, Wres, xwp, NNODES);
    res_gather<<<ngrid32, 256, 0, stream>>>(xwp, rp_s, csr_s, res, NNODES);

    // ---- 3 GCN layers: packed gemm -> fused gather+LN+ReLU ----
    for (int l = 0; l < 3; ++l) {
        gemm64p<<<2048, 256, 0, stream>>>(h, convW + l * HDIM * HDIM, xwp, NNODES);
        conv_ln<<<ngrid32, 256, 0, stream>>>(xwp, rp_d, csr_d, dinv,
                                             convB + l * HDIM, lng + l * HDIM,
                                             lnb + l * HDIM, h, NNODES);
    }

    // ---- out = h @ Wl + bl ----
    gemm64<<<2048, 256, 0, stream>>>(h, Wl, bl, out, NNODES, 0);
}